// Round 2
// baseline (336.349 us; speedup 1.0000x reference)
//
#include <hip/hip_runtime.h>
#include <hip/hip_bf16.h>

// B=32, C=128, HW=4096.
//   E = [wB;wV]@x + bias ; expB/expV = exp(E) (bf16) ; ZB/ZV row sums
//   T[i,c] = sum_n expB[i,n]*x[c,n]
//   G[i,j] = ((T[i,:].wA[j,:])/ZB_i + bA[j]) / (4096*ZV_i)
//   out[j,n] = sum_i expV[i,n]*G[i,j]
// R1: k1 rebuilt as 512-thread / 8-wave blocks (__launch_bounds__(512,4)) to
//     double occupancy (was 2 waves/SIMD, latency-bound: MfmaUtil 13%,
//     VALUBusy 19%, HBM 12%). Per-wave tiles halved: E 32 rows, T 64x32.
//     k4/k3b: G split reduced 3-term -> 2-term (Gtl dropped; error ~1e-10),
//     k4 __launch_bounds__(256,4) for 4 blocks/CU.

#define B_  32
#define C_  128
#define HW_ 4096

typedef __attribute__((ext_vector_type(8))) __bf16 bf16x8;
typedef __attribute__((ext_vector_type(4))) float f32x4;

__device__ __forceinline__ unsigned int bf_rne(float f) {   // bf16 bits (RNE)
    unsigned int u = __float_as_uint(f);
    return (u + 0x7fffu + ((u >> 16) & 1u)) >> 16;
}
__device__ __forceinline__ float bf_hi(float f) {           // RNE-to-bf16, as fp32
    unsigned int u = __float_as_uint(f);
    return __uint_as_float((u + 0x7fffu + ((u >> 16) & 1u)) & 0xffff0000u);
}

// ---------------------------------------------------------------------------
// k0: split Wcat=[wB;wV] (256x128 fp32) into bf16 hi/lo arrays. grid 32x256.
__global__ __launch_bounds__(256) void k0_prep(
    const float* __restrict__ wB, const float* __restrict__ wV,
    unsigned short* __restrict__ Wh, unsigned short* __restrict__ Wl)
{
    int g = blockIdx.x * 256 + threadIdx.x;      // 0..8191 float4s
    int row = g >> 5, c4 = (g & 31) << 2;
    const float* src = (row < 128) ? &wB[row * 128] : &wV[(row - 128) * 128];
    float4 v = *(const float4*)&src[c4];
    float vv[4] = {v.x, v.y, v.z, v.w};
    unsigned int h[4], l[4];
#pragma unroll
    for (int e = 0; e < 4; ++e) {
        float hf = bf_hi(vv[e]);
        h[e] = __float_as_uint(hf) >> 16;
        l[e] = bf_rne(vv[e] - hf);
    }
    *(uint2*)&Wh[row * 128 + c4] = make_uint2(h[0] | (h[1] << 16), h[2] | (h[3] << 16));
    *(uint2*)&Wl[row * 128 + c4] = make_uint2(l[0] | (l[1] << 16), l[2] | (l[3] << 16));
}

// ---------------------------------------------------------------------------
// k1_fused: E-GEMM + exp + Z + T-GEMM. grid (16 nchunks, 32 b), 512 thr = 8 waves.
// Per wave: E rows = 32 (mt=2), T tile = 64i x 32c (mt=4, ct=2).
__global__ __launch_bounds__(512, 4) void k1_fused(
    const float* __restrict__ x,
    const unsigned short* __restrict__ Wh, const unsigned short* __restrict__ Wl,
    const float* __restrict__ bB, const float* __restrict__ bV,
    unsigned short* __restrict__ expVT, float* __restrict__ T,
    float* __restrict__ Zcat)
{
    __shared__ unsigned short XT_h[32 * 136];   // [n][c] pitch 136 (E B-operand, hi)
    __shared__ unsigned short XT_l[32 * 136];
    __shared__ unsigned short XN_h[128 * 40];   // [c][n] pitch 40 (T B-operand, hi)
    __shared__ unsigned short XN_l[128 * 40];
    __shared__ unsigned short EBs[128 * 40];    // expB [i][n] pitch 40 (T A-operand)
    __shared__ unsigned short EVs[32 * 136];    // expV [n][i] pitch 136 (copy-out)

    const int t = threadIdx.x;
    const int lane = t & 63, w = t >> 6;        // w = 0..7
    const int col16 = lane & 15, quad = lane >> 4;
    const int b = blockIdx.y;
    const int n0 = blockIdx.x * 256;
    const float* xb = x + (size_t)b * C_ * HW_;

    const int sn = t & 31;        // staging: this thread's n within subtile
    const int cq0 = t >> 5;       // staging: c-block (0..15), owns 8 c values

    const int rowbase = w * 32;               // E rows for this wave (0..255)
    const int lbase = (w & 3) * 32;           // row base within 128-row projection
    const int mh = (w >> 2) * 64;             // T tile: i-half
    const int nh = (w & 3) * 32;              // T tile: c-quarter
    const float* bptr = (w < 4) ? bB : bV;

    float biasr[2][4];
#pragma unroll
    for (int mt = 0; mt < 2; ++mt)
#pragma unroll
        for (int r = 0; r < 4; ++r)
            biasr[mt][r] = bptr[lbase + mt * 16 + quad * 4 + r];

    f32x4 tacc[4][2];
    float zacc[2][4];
#pragma unroll
    for (int i = 0; i < 4; ++i)
#pragma unroll
        for (int j = 0; j < 2; ++j) tacc[i][j] = (f32x4){0.f,0.f,0.f,0.f};
#pragma unroll
    for (int i = 0; i < 2; ++i)
#pragma unroll
        for (int j = 0; j < 4; ++j) zacc[i][j] = 0.f;

    // prefetch subtile 0: thread owns x[c = cq0*8 + cc][n0 + sn]
    float xr[8];
#pragma unroll
    for (int cc = 0; cc < 8; ++cc)
        xr[cc] = xb[(size_t)(cq0 * 8 + cc) * HW_ + n0 + sn];

    for (int st = 0; st < 8; ++st) {
        // convert this subtile's x to bf16 hi/lo (pre-barrier: overlaps wait)
        unsigned int hbits[8], lbits[8];
#pragma unroll
        for (int e = 0; e < 8; ++e) {
            float hf = bf_hi(xr[e]);
            hbits[e] = __float_as_uint(hf) >> 16;
            lbits[e] = bf_rne(xr[e] - hf);
        }
        __syncthreads();   // previous subtile's T-MFMA / copy-out done
        {
            int cb = cq0 * 8;
            *(uint4*)&XT_h[sn * 136 + cb] = make_uint4(
                hbits[0] | (hbits[1] << 16), hbits[2] | (hbits[3] << 16),
                hbits[4] | (hbits[5] << 16), hbits[6] | (hbits[7] << 16));
            *(uint4*)&XT_l[sn * 136 + cb] = make_uint4(
                lbits[0] | (lbits[1] << 16), lbits[2] | (lbits[3] << 16),
                lbits[4] | (lbits[5] << 16), lbits[6] | (lbits[7] << 16));
            // XN [c][n]: scalar b16 scatter
#pragma unroll
            for (int cc = 0; cc < 8; ++cc) {
                int c = cb + cc;
                XN_h[c * 40 + sn] = (unsigned short)hbits[cc];
                XN_l[c * 40 + sn] = (unsigned short)lbits[cc];
            }
        }
        __syncthreads();
        // prefetch next subtile (overlaps E/T compute)
        if (st < 7) {
            int ns2 = n0 + (st + 1) * 32;
#pragma unroll
            for (int cc = 0; cc < 8; ++cc)
                xr[cc] = xb[(size_t)(cq0 * 8 + cc) * HW_ + ns2 + sn];
        }

        // --- E-GEMM: wave computes rows rowbase..+31 x 32 n, K=128 (c), 3 terms
        f32x4 eacc[2][2];
#pragma unroll
        for (int i = 0; i < 2; ++i)
#pragma unroll
            for (int j = 0; j < 2; ++j) eacc[i][j] = (f32x4){0.f,0.f,0.f,0.f};
#pragma unroll
        for (int ks = 0; ks < 4; ++ks) {
            int kc = ks * 32 + quad * 8;
            bf16x8 xh0 = *(const bf16x8*)&XT_h[col16 * 136 + kc];
            bf16x8 xl0 = *(const bf16x8*)&XT_l[col16 * 136 + kc];
            bf16x8 xh1 = *(const bf16x8*)&XT_h[(16 + col16) * 136 + kc];
            bf16x8 xl1 = *(const bf16x8*)&XT_l[(16 + col16) * 136 + kc];
#pragma unroll
            for (int mt = 0; mt < 2; ++mt) {
                int row = rowbase + mt * 16 + col16;
                bf16x8 wh = *(const bf16x8*)&Wh[row * 128 + kc];
                bf16x8 wl = *(const bf16x8*)&Wl[row * 128 + kc];
                eacc[mt][0] = __builtin_amdgcn_mfma_f32_16x16x32_bf16(wh, xh0, eacc[mt][0], 0, 0, 0);
                eacc[mt][0] = __builtin_amdgcn_mfma_f32_16x16x32_bf16(wh, xl0, eacc[mt][0], 0, 0, 0);
                eacc[mt][0] = __builtin_amdgcn_mfma_f32_16x16x32_bf16(wl, xh0, eacc[mt][0], 0, 0, 0);
                eacc[mt][1] = __builtin_amdgcn_mfma_f32_16x16x32_bf16(wh, xh1, eacc[mt][1], 0, 0, 0);
                eacc[mt][1] = __builtin_amdgcn_mfma_f32_16x16x32_bf16(wh, xl1, eacc[mt][1], 0, 0, 0);
                eacc[mt][1] = __builtin_amdgcn_mfma_f32_16x16x32_bf16(wl, xh1, eacc[mt][1], 0, 0, 0);
            }
        }

        // --- epilogue: exp, Z accumulate, expB->EBs / expV->EVs
#pragma unroll
        for (int mt = 0; mt < 2; ++mt)
#pragma unroll
            for (int r = 0; r < 4; ++r) {
                int lrow = lbase + mt * 16 + quad * 4 + r;   // 0..127 within proj
                float e0 = __expf(eacc[mt][0][r] + biasr[mt][r]);
                float e1 = __expf(eacc[mt][1][r] + biasr[mt][r]);
                zacc[mt][r] += e0 + e1;
                if (w < 4) {
                    EBs[lrow * 40 + col16]      = (unsigned short)bf_rne(e0);
                    EBs[lrow * 40 + 16 + col16] = (unsigned short)bf_rne(e1);
                } else {
                    EVs[col16 * 136 + lrow]        = (unsigned short)bf_rne(e0);
                    EVs[(16 + col16) * 136 + lrow] = (unsigned short)bf_rne(e1);
                }
            }
        __syncthreads();   // EBs/EVs ready; XN still valid

        // --- T-GEMM: K=32 (this subtile's n), wave tile 64 i x 32 c
        {
            bf16x8 a[4];
#pragma unroll
            for (int mt = 0; mt < 4; ++mt)
                a[mt] = *(const bf16x8*)&EBs[(mh + mt * 16 + col16) * 40 + quad * 8];
#pragma unroll
            for (int ct = 0; ct < 2; ++ct) {
                int c = nh + ct * 16 + col16;
                bf16x8 bh = *(const bf16x8*)&XN_h[c * 40 + quad * 8];
                bf16x8 bl = *(const bf16x8*)&XN_l[c * 40 + quad * 8];
#pragma unroll
                for (int mt = 0; mt < 4; ++mt) {
                    tacc[mt][ct] = __builtin_amdgcn_mfma_f32_16x16x32_bf16(a[mt], bh, tacc[mt][ct], 0, 0, 0);
                    tacc[mt][ct] = __builtin_amdgcn_mfma_f32_16x16x32_bf16(a[mt], bl, tacc[mt][ct], 0, 0, 0);
                }
            }
        }
        // --- expVT copy-out (32 n x 128 i), one uint4 per thread
        {
            int n = t >> 4, ig = t & 15;
            *(uint4*)&expVT[((size_t)b * HW_ + n0 + st * 32 + n) * 128 + ig * 8] =
                *(const uint4*)&EVs[n * 136 + ig * 8];
        }
    }

    // Z atomics (one per row, reduced across col16 lanes first)
    const int zoff = (w < 4) ? 0 : 128;
#pragma unroll
    for (int mt = 0; mt < 2; ++mt)
#pragma unroll
        for (int r = 0; r < 4; ++r) {
            float rs = zacc[mt][r];
            rs += __shfl_xor(rs, 1, 16);
            rs += __shfl_xor(rs, 2, 16);
            rs += __shfl_xor(rs, 4, 16);
            rs += __shfl_xor(rs, 8, 16);
            if (col16 == 0)
                atomicAdd(&Zcat[b * 256 + zoff + lbase + mt * 16 + quad * 4 + r], rs);
        }
    // T atomics
#pragma unroll
    for (int mt = 0; mt < 4; ++mt)
#pragma unroll
        for (int ct = 0; ct < 2; ++ct)
#pragma unroll
            for (int r = 0; r < 4; ++r)
                atomicAdd(&T[((size_t)b * 128 + mh + mt * 16 + quad * 4 + r) * 128 + nh + ct * 16 + col16],
                          tacc[mt][ct][r]);
}

// ---------------------------------------------------------------------------
// k3b: G transposed + 2-way bf16 split. grid (4, 32), block 256, fp32 VALU.
__global__ __launch_bounds__(256) void k3b_G(
    const float* __restrict__ T, const float* __restrict__ wA, const float* __restrict__ bA,
    const float* __restrict__ Zcat,
    unsigned short* __restrict__ Gth, unsigned short* __restrict__ Gtm)
{
    const int t = threadIdx.x;
    const int tx = t & 15, ty = t >> 4;
    const int b = blockIdx.y;
    const int jb = (blockIdx.x >> 1) * 64;
    const int ib = (blockIdx.x & 1) * 64;

    __shared__ float Ts[64][36];
    __shared__ float Wa[64][36];

    float acc[4][4];
#pragma unroll
    for (int i = 0; i < 4; ++i)
#pragma unroll
        for (int j = 0; j < 4; ++j) acc[i][j] = 0.f;

    for (int c0 = 0; c0 < 128; c0 += 32) {
        __syncthreads();
#pragma unroll
        for (int it = 0; it < 2; ++it) {
            int idx = it * 256 + t;
            int r = idx >> 3, kq = (idx & 7) << 2;
            *(float4*)&Ts[r][kq] = *(const float4*)&T[((size_t)b * 128 + ib + r) * 128 + c0 + kq];
        }
#pragma unroll
        for (int it = 0; it < 2; ++it) {
            int idx = it * 256 + t;
            int r = idx >> 3, kq = (idx & 7) << 2;
            *(float4*)&Wa[r][kq] = *(const float4*)&wA[(jb + r) * 128 + c0 + kq];
        }
        __syncthreads();
#pragma unroll
        for (int k = 0; k < 32; k += 4) {
            float4 wv[4], tv[4];
#pragma unroll
            for (int jj = 0; jj < 4; ++jj) wv[jj] = *(const float4*)&Wa[jj * 16 + ty][k];
#pragma unroll
            for (int ii = 0; ii < 4; ++ii) tv[ii] = *(const float4*)&Ts[ii * 16 + tx][k];
#pragma unroll
            for (int jj = 0; jj < 4; ++jj)
#pragma unroll
                for (int ii = 0; ii < 4; ++ii) {
                    acc[jj][ii] = fmaf(wv[jj].x, tv[ii].x, acc[jj][ii]);
                    acc[jj][ii] = fmaf(wv[jj].y, tv[ii].y, acc[jj][ii]);
                    acc[jj][ii] = fmaf(wv[jj].z, tv[ii].z, acc[jj][ii]);
                    acc[jj][ii] = fmaf(wv[jj].w, tv[ii].w, acc[jj][ii]);
                }
        }
    }
    const float* ZB = Zcat + b * 256;
    const float* ZV = ZB + 128;
#pragma unroll
    for (int jj = 0; jj < 4; ++jj) {
        int j = jb + jj * 16 + ty;
        float bj = bA[j];
#pragma unroll
        for (int ii = 0; ii < 4; ++ii) {
            int i = ib + ii * 16 + tx;
            float g = (acc[jj][ii] / ZB[i] + bj) / (4096.f * ZV[i]);
            float h = bf_hi(g);  float r1 = g - h;
            float m = bf_hi(r1);
            size_t o = ((size_t)b * 128 + j) * 128 + i;
            Gth[o] = (unsigned short)(__float_as_uint(h) >> 16);
            Gtm[o] = (unsigned short)(__float_as_uint(m) >> 16);
        }
    }
}

// ---------------------------------------------------------------------------
// k4: out[b,j,n] = sum_i expVT[n][i] * Gt(j,i)  (MFMA, 2-term G split).
__global__ __launch_bounds__(256, 4) void k4_out(
    const unsigned short* __restrict__ expVT,
    const unsigned short* __restrict__ Gth, const unsigned short* __restrict__ Gtm,
    float* __restrict__ out)
{
    __shared__ unsigned short Vs[128 * 136];   // [n][i] pitch 136

    const int t = threadIdx.x;
    const int lane = t & 63, w = t >> 6;
    const int col16 = lane & 15, quad = lane >> 4;
    const int b = blockIdx.y, nb = blockIdx.x * 128;

#pragma unroll
    for (int it = 0; it < 8; ++it) {
        int idx = it * 256 + t;
        int n = idx >> 4, o = idx & 15;
        int o2 = (o + 4 * (n & 3)) & 15;
        *(uint4*)&Vs[n * 136 + o2 * 8] =
            *(const uint4*)&expVT[((size_t)b * HW_ + nb + n) * 128 + o2 * 8];
    }
    __syncthreads();

    f32x4 acc[8][2];
#pragma unroll
    for (int i = 0; i < 8; ++i)
#pragma unroll
        for (int j = 0; j < 2; ++j) acc[i][j] = (f32x4){0.f,0.f,0.f,0.f};

    const unsigned short* gh = Gth + (size_t)b * 128 * 128;
    const unsigned short* gm = Gtm + (size_t)b * 128 * 128;

#pragma unroll
    for (int ks = 0; ks < 4; ++ks) {
        int ko = ks * 32 + quad * 8;
        bf16x8 vfr[2];
#pragma unroll
        for (int nt = 0; nt < 2; ++nt) {
            int n = w * 32 + nt * 16 + col16;
            vfr[nt] = *(const bf16x8*)&Vs[n * 136 + ko];
        }
#pragma unroll
        for (int mt = 0; mt < 8; ++mt) {
            int j = mt * 16 + col16;
            bf16x8 ah = *(const bf16x8*)&gh[j * 128 + ko];
            bf16x8 am = *(const bf16x8*)&gm[j * 128 + ko];
#pragma unroll
            for (int nt = 0; nt < 2; ++nt) {
                acc[mt][nt] = __builtin_amdgcn_mfma_f32_16x16x32_bf16(ah, vfr[nt], acc[mt][nt], 0, 0, 0);
                acc[mt][nt] = __builtin_amdgcn_mfma_f32_16x16x32_bf16(am, vfr[nt], acc[mt][nt], 0, 0, 0);
            }
        }
    }
    float* ob = out + (size_t)b * C_ * HW_;
#pragma unroll
    for (int mt = 0; mt < 8; ++mt)
#pragma unroll
        for (int nt = 0; nt < 2; ++nt)
#pragma unroll
            for (int r = 0; r < 4; ++r) {
                int j = mt * 16 + quad * 4 + r;
                int n = nb + w * 32 + nt * 16 + col16;
                ob[(size_t)j * HW_ + n] = acc[mt][nt][r];
            }
}

// ---------------------------------------------------------------------------
extern "C" void kernel_launch(void* const* d_in, const int* in_sizes, int n_in,
                              void* d_out, int out_size, void* d_ws, size_t ws_size,
                              hipStream_t stream)
{
    const float* x  = (const float*)d_in[0];
    const float* wA = (const float*)d_in[1];
    const float* bA = (const float*)d_in[2];
    const float* wB = (const float*)d_in[3];
    const float* bB = (const float*)d_in[4];
    const float* wV = (const float*)d_in[5];
    const float* bV = (const float*)d_in[6];
    float* out = (float*)d_out;

    // workspace (~39 MiB):
    //   Zcat 32 KiB | T 2 MiB | Wh 64 KiB | Wl 64 KiB | expVT 32 MiB | Gth/Gtm 2 MiB
    char* ws = (char*)d_ws;
    float*          Zcat  = (float*)ws;
    float*          T     = (float*)(ws + 32768);
    unsigned short* Wh    = (unsigned short*)(ws + 2129920);
    unsigned short* Wl    = (unsigned short*)(ws + 2195456);
    unsigned short* expVT = (unsigned short*)(ws + 2260992);
    unsigned short* Gth   = (unsigned short*)(ws + 2260992 + 33554432);
    unsigned short* Gtm   = Gth + 128 * 128 * 32;

    hipMemsetAsync(Zcat, 0, 2129920, stream);   // Zcat + T

    k0_prep <<<dim3(32),     256, 0, stream>>>(wB, wV, Wh, Wl);
    k1_fused<<<dim3(16, 32), 512, 0, stream>>>(x, Wh, Wl, bB, bV, expVT, T, Zcat);
    k3b_G   <<<dim3(4, 32),  256, 0, stream>>>(T, wA, bA, Zcat, Gth, Gtm);
    k4_out  <<<dim3(32, 32), 256, 0, stream>>>(expVT, Gth, Gtm, out);
}

// Round 3
// 257.124 us; speedup vs baseline: 1.3081x; 1.3081x over previous
//
#include <hip/hip_runtime.h>
#include <hip/hip_bf16.h>

// B=32, C=128, HW=4096.
//   E = [wB;wV]@x + bias ; expB/expV = exp(E) (bf16) ; ZB/ZV row sums
//   T[i,c] = sum_n expB[i,n]*x[c,n]
//   G[i,j] = ((T[i,:].wA[j,:])/ZB_i + bA[j]) / (4096*ZV_i)
//   out[j,n] = sum_i expV[i,n]*G[i,j]
// R3: k1's T-GEMM split into k2. Rationale (R1/R2 counters): tacc[4][4]=64
//   VGPR kept k1 at 204 regs -> 2 waves/SIMD, latency-bound (MfmaUtil 13%);
//   forcing a cap (R2) spilled (FETCH 8x). Now k1 ~= E+exp+copyout (~110 regs,
//   2 barriers/subtile, no XN scatter, no T atomics), expB round-trips via L3.
//   k2 = T-GEMM with clean contiguous-n staging, writes T partials (no
//   atomics); k2b reduces partials; k3b regridded to 256 blocks.

#define B_  32
#define C_  128
#define HW_ 4096

typedef __attribute__((ext_vector_type(8))) __bf16 bf16x8;
typedef __attribute__((ext_vector_type(4))) float f32x4;

__device__ __forceinline__ unsigned int bf_rne(float f) {   // bf16 bits (RNE)
    unsigned int u = __float_as_uint(f);
    return (u + 0x7fffu + ((u >> 16) & 1u)) >> 16;
}
__device__ __forceinline__ float bf_hi(float f) {           // RNE-to-bf16, as fp32
    unsigned int u = __float_as_uint(f);
    return __uint_as_float((u + 0x7fffu + ((u >> 16) & 1u)) & 0xffff0000u);
}

// ---------------------------------------------------------------------------
// k0: split Wcat=[wB;wV] (256x128 fp32) into bf16 hi/lo arrays. grid 32x256.
__global__ __launch_bounds__(256) void k0_prep(
    const float* __restrict__ wB, const float* __restrict__ wV,
    unsigned short* __restrict__ Wh, unsigned short* __restrict__ Wl)
{
    int g = blockIdx.x * 256 + threadIdx.x;      // 0..8191 float4s
    int row = g >> 5, c4 = (g & 31) << 2;
    const float* src = (row < 128) ? &wB[row * 128] : &wV[(row - 128) * 128];
    float4 v = *(const float4*)&src[c4];
    float vv[4] = {v.x, v.y, v.z, v.w};
    unsigned int h[4], l[4];
#pragma unroll
    for (int e = 0; e < 4; ++e) {
        float hf = bf_hi(vv[e]);
        h[e] = __float_as_uint(hf) >> 16;
        l[e] = bf_rne(vv[e] - hf);
    }
    *(uint2*)&Wh[row * 128 + c4] = make_uint2(h[0] | (h[1] << 16), h[2] | (h[3] << 16));
    *(uint2*)&Wl[row * 128 + c4] = make_uint2(l[0] | (l[1] << 16), l[2] | (l[3] << 16));
}

// ---------------------------------------------------------------------------
// k1_fused: E-GEMM + exp + Z + expB/expVT copy-out. grid (16, 32), 256 thr.
// Per wave: 64 E-rows (mt=4), 32 n. No T-GEMM (see k2).
__global__ __launch_bounds__(256) void k1_fused(
    const float* __restrict__ x,
    const unsigned short* __restrict__ Wh, const unsigned short* __restrict__ Wl,
    const float* __restrict__ bB, const float* __restrict__ bV,
    unsigned short* __restrict__ expB, unsigned short* __restrict__ expVT,
    float* __restrict__ Zcat)
{
    __shared__ unsigned short XT_h[32 * 136];   // [n][c] pitch 136 (E B-operand, hi)
    __shared__ unsigned short XT_l[32 * 136];
    __shared__ unsigned short EBs[128 * 40];    // expB [i][n] pitch 40
    __shared__ unsigned short EVs[32 * 136];    // expV [n][i] pitch 136
    __shared__ float bias_s[256];

    const int t = threadIdx.x;
    const int lane = t & 63, w = t >> 6;        // w = 0..3
    const int col16 = lane & 15, quad = lane >> 4;
    const int b = blockIdx.y;
    const int n0 = blockIdx.x * 256;
    const float* xb = x + (size_t)b * C_ * HW_;

    const int sn = t & 31;        // staging: this thread's n within subtile
    const int cq0 = t >> 5;       // staging: c-block base (0..7)

    const int rowbase = w * 64;               // E rows for this wave (0..255)
    const int lbase = (w & 1) * 64;           // row base within 128-row projection
    const int boff = (w < 2) ? 0 : 128;

    bias_s[t] = (t < 128) ? bB[t] : bV[t - 128];   // visible after first barrier

    float zacc[4][4];
#pragma unroll
    for (int i = 0; i < 4; ++i)
#pragma unroll
        for (int j = 0; j < 4; ++j) zacc[i][j] = 0.f;

    // prefetch subtile 0: thread owns x[c = (cq0+8*i2)*8 + cc][n0 + sn]
    float xr[16];
#pragma unroll
    for (int i2 = 0; i2 < 2; ++i2)
#pragma unroll
        for (int cc = 0; cc < 8; ++cc)
            xr[i2 * 8 + cc] = xb[(size_t)((cq0 + i2 * 8) * 8 + cc) * HW_ + n0 + sn];

    for (int st = 0; st < 8; ++st) {
        // convert this subtile's x to bf16 hi/lo
        unsigned int hbits[16], lbits[16];
#pragma unroll
        for (int e = 0; e < 16; ++e) {
            float hf = bf_hi(xr[e]);
            hbits[e] = __float_as_uint(hf) >> 16;
            lbits[e] = bf_rne(xr[e] - hf);
        }
        __syncthreads();   // B1: previous subtile's XT reads / EB,EV copy-out done
#pragma unroll
        for (int i2 = 0; i2 < 2; ++i2) {
            const unsigned int* h = &hbits[i2 * 8];
            const unsigned int* l = &lbits[i2 * 8];
            int cb = (cq0 + i2 * 8) * 8;
            *(uint4*)&XT_h[sn * 136 + cb] = make_uint4(
                h[0] | (h[1] << 16), h[2] | (h[3] << 16), h[4] | (h[5] << 16), h[6] | (h[7] << 16));
            *(uint4*)&XT_l[sn * 136 + cb] = make_uint4(
                l[0] | (l[1] << 16), l[2] | (l[3] << 16), l[4] | (l[5] << 16), l[6] | (l[7] << 16));
        }
        __syncthreads();   // B2: XT visible
        // prefetch next subtile (overlaps E compute)
        if (st < 7) {
            int ns2 = n0 + (st + 1) * 32;
#pragma unroll
            for (int i2 = 0; i2 < 2; ++i2)
#pragma unroll
                for (int cc = 0; cc < 8; ++cc)
                    xr[i2 * 8 + cc] = xb[(size_t)((cq0 + i2 * 8) * 8 + cc) * HW_ + ns2 + sn];
        }

        // --- E-GEMM: wave computes rows rowbase..+63 x 32 n, K=128 (c), 3 terms
        f32x4 eacc[4][2];
#pragma unroll
        for (int i = 0; i < 4; ++i)
#pragma unroll
            for (int j = 0; j < 2; ++j) eacc[i][j] = (f32x4){0.f,0.f,0.f,0.f};
#pragma unroll
        for (int ks = 0; ks < 4; ++ks) {
            int kc = ks * 32 + quad * 8;
            bf16x8 xh0 = *(const bf16x8*)&XT_h[col16 * 136 + kc];
            bf16x8 xl0 = *(const bf16x8*)&XT_l[col16 * 136 + kc];
            bf16x8 xh1 = *(const bf16x8*)&XT_h[(16 + col16) * 136 + kc];
            bf16x8 xl1 = *(const bf16x8*)&XT_l[(16 + col16) * 136 + kc];
#pragma unroll
            for (int mt = 0; mt < 4; ++mt) {
                int row = rowbase + mt * 16 + col16;
                bf16x8 wh = *(const bf16x8*)&Wh[row * 128 + kc];
                bf16x8 wl = *(const bf16x8*)&Wl[row * 128 + kc];
                eacc[mt][0] = __builtin_amdgcn_mfma_f32_16x16x32_bf16(wh, xh0, eacc[mt][0], 0, 0, 0);
                eacc[mt][0] = __builtin_amdgcn_mfma_f32_16x16x32_bf16(wh, xl0, eacc[mt][0], 0, 0, 0);
                eacc[mt][0] = __builtin_amdgcn_mfma_f32_16x16x32_bf16(wl, xh0, eacc[mt][0], 0, 0, 0);
                eacc[mt][1] = __builtin_amdgcn_mfma_f32_16x16x32_bf16(wh, xh1, eacc[mt][1], 0, 0, 0);
                eacc[mt][1] = __builtin_amdgcn_mfma_f32_16x16x32_bf16(wh, xl1, eacc[mt][1], 0, 0, 0);
                eacc[mt][1] = __builtin_amdgcn_mfma_f32_16x16x32_bf16(wl, xh1, eacc[mt][1], 0, 0, 0);
            }
        }

        // --- epilogue: exp, Z accumulate, expB->EBs [i][n] / expV->EVs [n][i]
#pragma unroll
        for (int mt = 0; mt < 4; ++mt)
#pragma unroll
            for (int r = 0; r < 4; ++r) {
                int lrow = lbase + mt * 16 + quad * 4 + r;   // 0..127 within proj
                float bb = bias_s[boff + lrow];
                float e0 = __expf(eacc[mt][0][r] + bb);
                float e1 = __expf(eacc[mt][1][r] + bb);
                zacc[mt][r] += e0 + e1;
                if (w < 2) {
                    EBs[lrow * 40 + col16]      = (unsigned short)bf_rne(e0);
                    EBs[lrow * 40 + 16 + col16] = (unsigned short)bf_rne(e1);
                } else {
                    EVs[col16 * 136 + lrow]        = (unsigned short)bf_rne(e0);
                    EVs[(16 + col16) * 136 + lrow] = (unsigned short)bf_rne(e1);
                }
            }
        // --- wave-local copy-out (reads only rows this wave wrote; per-wave
        //     in-order LDS => no barrier needed; B1 next iter protects reuse)
        if (w < 2) {
            // expB [b][i][n], this wave's i in [w*64, w*64+64)
#pragma unroll
            for (int rep = 0; rep < 4; ++rep) {
                int idx = rep * 64 + lane;
                int il = idx >> 2, nc = idx & 3;
                *(uint4*)&expB[((size_t)b * 128 + w * 64 + il) * HW_ + n0 + st * 32 + nc * 8] =
                    *(const uint4*)&EBs[(w * 64 + il) * 40 + nc * 8];
            }
        } else {
            // expVT [b][n][i], this wave's i-half hv
            int hv = (w & 1) * 64;
#pragma unroll
            for (int rep = 0; rep < 4; ++rep) {
                int idx = rep * 64 + lane;
                int nl = idx >> 3, i8 = idx & 7;
                *(uint4*)&expVT[((size_t)b * HW_ + n0 + st * 32 + nl) * 128 + hv + i8 * 8] =
                    *(const uint4*)&EVs[nl * 136 + hv + i8 * 8];
            }
        }
    }

    // Z atomics (one per row, reduced across col16 lanes first)
#pragma unroll
    for (int mt = 0; mt < 4; ++mt)
#pragma unroll
        for (int r = 0; r < 4; ++r) {
            float rs = zacc[mt][r];
            rs += __shfl_xor(rs, 1, 16);
            rs += __shfl_xor(rs, 2, 16);
            rs += __shfl_xor(rs, 4, 16);
            rs += __shfl_xor(rs, 8, 16);
            if (col16 == 0)
                atomicAdd(&Zcat[b * 256 + boff + lbase + mt * 16 + quad * 4 + r], rs);
        }
}

// ---------------------------------------------------------------------------
// k2_T: T_part[p][b][i][c] = sum_{n in chunk p} expB[i,n]*x[c,n].
// grid (np, 32), 256 thr = 4 waves, wave tile 64i x 64c, K-subtiles of 32 n.
__global__ __launch_bounds__(256) void k2_T(
    const float* __restrict__ x, const unsigned short* __restrict__ expB,
    float* __restrict__ T_part, int np)
{
    __shared__ unsigned short XN_h[128 * 40];   // [c][n] pitch 40
    __shared__ unsigned short XN_l[128 * 40];

    const int t = threadIdx.x;
    const int lane = t & 63, w = t >> 6;
    const int col16 = lane & 15, quad = lane >> 4;
    const int b = blockIdx.y, p = blockIdx.x;
    const int nchunk = HW_ / np;
    const int n0 = p * nchunk;
    const int nsub = nchunk / 32;
    const float* xb = x + (size_t)b * C_ * HW_;
    const unsigned short* eb = expB + (size_t)b * C_ * HW_;

    const int mh = (w >> 1) * 64;             // i-half
    const int nh = (w & 1) * 64;              // c-half
    const int sc = t >> 1, shf = (t & 1) * 16;   // staging: c row, n half

    f32x4 tacc[4][4];
#pragma unroll
    for (int i = 0; i < 4; ++i)
#pragma unroll
        for (int j = 0; j < 4; ++j) tacc[i][j] = (f32x4){0.f,0.f,0.f,0.f};

    // prefetch subtile 0: 16 consecutive n for row sc
    float xr[16];
#pragma unroll
    for (int q = 0; q < 4; ++q)
        *(float4*)&xr[q * 4] = *(const float4*)&xb[(size_t)sc * HW_ + n0 + shf + q * 4];

    for (int st = 0; st < nsub; ++st) {
        unsigned int hbits[16], lbits[16];
#pragma unroll
        for (int e = 0; e < 16; ++e) {
            float hf = bf_hi(xr[e]);
            hbits[e] = __float_as_uint(hf) >> 16;
            lbits[e] = bf_rne(xr[e] - hf);
        }
        // A frags for this subtile (global, L3-resident; latency hidden by barriers)
        bf16x8 a[4];
#pragma unroll
        for (int mt = 0; mt < 4; ++mt)
            a[mt] = *(const bf16x8*)&eb[(size_t)(mh + mt * 16 + col16) * HW_ + n0 + st * 32 + quad * 8];

        __syncthreads();   // B1: previous subtile's XN reads done
#pragma unroll
        for (int hx = 0; hx < 2; ++hx) {
            const unsigned int* s = hx ? lbits : hbits;
            unsigned short* dst = hx ? XN_l : XN_h;
            *(uint4*)&dst[sc * 40 + shf] = make_uint4(
                s[0] | (s[1] << 16), s[2] | (s[3] << 16), s[4] | (s[5] << 16), s[6] | (s[7] << 16));
            *(uint4*)&dst[sc * 40 + shf + 8] = make_uint4(
                s[8] | (s[9] << 16), s[10] | (s[11] << 16), s[12] | (s[13] << 16), s[14] | (s[15] << 16));
        }
        __syncthreads();   // B2: XN visible
        if (st < nsub - 1) {
            int ns2 = n0 + (st + 1) * 32;
#pragma unroll
            for (int q = 0; q < 4; ++q)
                *(float4*)&xr[q * 4] = *(const float4*)&xb[(size_t)sc * HW_ + ns2 + shf + q * 4];
        }

        // --- T-GEMM: K=32 (this subtile), wave tile 64 i x 64 c
#pragma unroll
        for (int ct = 0; ct < 4; ++ct) {
            int c = nh + ct * 16 + col16;
            bf16x8 bh = *(const bf16x8*)&XN_h[c * 40 + quad * 8];
            bf16x8 bl = *(const bf16x8*)&XN_l[c * 40 + quad * 8];
#pragma unroll
            for (int mt = 0; mt < 4; ++mt) {
                tacc[mt][ct] = __builtin_amdgcn_mfma_f32_16x16x32_bf16(a[mt], bh, tacc[mt][ct], 0, 0, 0);
                tacc[mt][ct] = __builtin_amdgcn_mfma_f32_16x16x32_bf16(a[mt], bl, tacc[mt][ct], 0, 0, 0);
            }
        }
    }

    // store partials (no atomics)
    float* Tp = T_part + ((size_t)p * B_ + b) * 128 * 128;
#pragma unroll
    for (int mt = 0; mt < 4; ++mt)
#pragma unroll
        for (int ct = 0; ct < 4; ++ct)
#pragma unroll
            for (int r = 0; r < 4; ++r)
                Tp[(mh + mt * 16 + quad * 4 + r) * 128 + nh + ct * 16 + col16] = tacc[mt][ct][r];
}

// ---------------------------------------------------------------------------
// k2b: T = sum_p T_part[p]. grid 512, 256 thr, one float4 per thread.
__global__ __launch_bounds__(256) void k2b_red(
    const float* __restrict__ T_part, float* __restrict__ T, int np)
{
    int g = blockIdx.x * 256 + threadIdx.x;     // 0..131071
    size_t o = (size_t)g * 4;
    float4 s = make_float4(0.f, 0.f, 0.f, 0.f);
    for (int p = 0; p < np; ++p) {
        float4 v = *(const float4*)&T_part[(size_t)p * (B_ * 128 * 128) + o];
        s.x += v.x; s.y += v.y; s.z += v.z; s.w += v.w;
    }
    *(float4*)&T[o] = s;
}

// ---------------------------------------------------------------------------
// k3b: G transposed + 2-way bf16 split. grid (8, 32), block 256, fp32 VALU.
// Tiles 64 j x 32 i (256 blocks = full GPU; was 128).
__global__ __launch_bounds__(256) void k3b_G(
    const float* __restrict__ T, const float* __restrict__ wA, const float* __restrict__ bA,
    const float* __restrict__ Zcat,
    unsigned short* __restrict__ Gth, unsigned short* __restrict__ Gtm)
{
    const int t = threadIdx.x;
    const int tx = t & 15, ty = t >> 4;
    const int b = blockIdx.y;
    const int jb = (blockIdx.x >> 2) * 64;
    const int ib = (blockIdx.x & 3) * 32;

    __shared__ float Ts[32][36];
    __shared__ float Wa[64][36];

    float acc[4][2];
#pragma unroll
    for (int i = 0; i < 4; ++i)
#pragma unroll
        for (int j = 0; j < 2; ++j) acc[i][j] = 0.f;

    for (int c0 = 0; c0 < 128; c0 += 32) {
        __syncthreads();
        {
            int r = t >> 3, kq = (t & 7) << 2;
            *(float4*)&Ts[r][kq] = *(const float4*)&T[((size_t)b * 128 + ib + r) * 128 + c0 + kq];
        }
#pragma unroll
        for (int it = 0; it < 2; ++it) {
            int idx = it * 256 + t;
            int r = idx >> 3, kq = (idx & 7) << 2;
            *(float4*)&Wa[r][kq] = *(const float4*)&wA[(jb + r) * 128 + c0 + kq];
        }
        __syncthreads();
#pragma unroll
        for (int k = 0; k < 32; k += 4) {
            float4 wv[4], tv[2];
#pragma unroll
            for (int jj = 0; jj < 4; ++jj) wv[jj] = *(const float4*)&Wa[jj * 16 + ty][k];
#pragma unroll
            for (int ii = 0; ii < 2; ++ii) tv[ii] = *(const float4*)&Ts[ii * 16 + tx][k];
#pragma unroll
            for (int jj = 0; jj < 4; ++jj)
#pragma unroll
                for (int ii = 0; ii < 2; ++ii) {
                    acc[jj][ii] = fmaf(wv[jj].x, tv[ii].x, acc[jj][ii]);
                    acc[jj][ii] = fmaf(wv[jj].y, tv[ii].y, acc[jj][ii]);
                    acc[jj][ii] = fmaf(wv[jj].z, tv[ii].z, acc[jj][ii]);
                    acc[jj][ii] = fmaf(wv[jj].w, tv[ii].w, acc[jj][ii]);
                }
        }
    }
    const float* ZB = Zcat + b * 256;
    const float* ZV = ZB + 128;
#pragma unroll
    for (int jj = 0; jj < 4; ++jj) {
        int j = jb + jj * 16 + ty;
        float bj = bA[j];
#pragma unroll
        for (int ii = 0; ii < 2; ++ii) {
            int i = ib + ii * 16 + tx;
            float g = (acc[jj][ii] / ZB[i] + bj) / (4096.f * ZV[i]);
            float h = bf_hi(g);  float r1 = g - h;
            float m = bf_hi(r1);
            size_t o = ((size_t)b * 128 + j) * 128 + i;
            Gth[o] = (unsigned short)(__float_as_uint(h) >> 16);
            Gtm[o] = (unsigned short)(__float_as_uint(m) >> 16);
        }
    }
}

// ---------------------------------------------------------------------------
// k4: out[b,j,n] = sum_i expVT[n][i] * Gt(j,i)  (MFMA, 2-term G split).
__global__ __launch_bounds__(256, 4) void k4_out(
    const unsigned short* __restrict__ expVT,
    const unsigned short* __restrict__ Gth, const unsigned short* __restrict__ Gtm,
    float* __restrict__ out)
{
    __shared__ unsigned short Vs[128 * 136];   // [n][i] pitch 136

    const int t = threadIdx.x;
    const int lane = t & 63, w = t >> 6;
    const int col16 = lane & 15, quad = lane >> 4;
    const int b = blockIdx.y, nb = blockIdx.x * 128;

#pragma unroll
    for (int it = 0; it < 8; ++it) {
        int idx = it * 256 + t;
        int n = idx >> 4, o = idx & 15;
        int o2 = (o + 4 * (n & 3)) & 15;
        *(uint4*)&Vs[n * 136 + o2 * 8] =
            *(const uint4*)&expVT[((size_t)b * HW_ + nb + n) * 128 + o2 * 8];
    }
    __syncthreads();

    f32x4 acc[8][2];
#pragma unroll
    for (int i = 0; i < 8; ++i)
#pragma unroll
        for (int j = 0; j < 2; ++j) acc[i][j] = (f32x4){0.f,0.f,0.f,0.f};

    const unsigned short* gh = Gth + (size_t)b * 128 * 128;
    const unsigned short* gm = Gtm + (size_t)b * 128 * 128;

#pragma unroll
    for (int ks = 0; ks < 4; ++ks) {
        int ko = ks * 32 + quad * 8;
        bf16x8 vfr[2];
#pragma unroll
        for (int nt = 0; nt < 2; ++nt) {
            int n = w * 32 + nt * 16 + col16;
            vfr[nt] = *(const bf16x8*)&Vs[n * 136 + ko];
        }
#pragma unroll
        for (int mt = 0; mt < 8; ++mt) {
            int j = mt * 16 + col16;
            bf16x8 ah = *(const bf16x8*)&gh[j * 128 + ko];
            bf16x8 am = *(const bf16x8*)&gm[j * 128 + ko];
#pragma unroll
            for (int nt = 0; nt < 2; ++nt) {
                acc[mt][nt] = __builtin_amdgcn_mfma_f32_16x16x32_bf16(ah, vfr[nt], acc[mt][nt], 0, 0, 0);
                acc[mt][nt] = __builtin_amdgcn_mfma_f32_16x16x32_bf16(am, vfr[nt], acc[mt][nt], 0, 0, 0);
            }
        }
    }
    float* ob = out + (size_t)b * C_ * HW_;
#pragma unroll
    for (int mt = 0; mt < 8; ++mt)
#pragma unroll
        for (int nt = 0; nt < 2; ++nt)
#pragma unroll
            for (int r = 0; r < 4; ++r) {
                int j = mt * 16 + quad * 4 + r;
                int n = nb + w * 32 + nt * 16 + col16;
                ob[(size_t)j * HW_ + n] = acc[mt][nt][r];
            }
}

// ---------------------------------------------------------------------------
extern "C" void kernel_launch(void* const* d_in, const int* in_sizes, int n_in,
                              void* d_out, int out_size, void* d_ws, size_t ws_size,
                              hipStream_t stream)
{
    const float* x  = (const float*)d_in[0];
    const float* wA = (const float*)d_in[1];
    const float* bA = (const float*)d_in[2];
    const float* wB = (const float*)d_in[3];
    const float* bB = (const float*)d_in[4];
    const float* wV = (const float*)d_in[5];
    const float* bV = (const float*)d_in[6];
    float* out = (float*)d_out;

    // workspace (~100 MiB at np=16):
    //   Zcat 32K | Wh 64K | Wl 64K | T 2M | expB 32M | expVT 32M | T_part np*2M | G 2M
    char* ws = (char*)d_ws;
    float*          Zcat  = (float*)ws;                       // 32768
    unsigned short* Wh    = (unsigned short*)(ws + 32768);    // 65536
    unsigned short* Wl    = (unsigned short*)(ws + 98304);    // 65536
    float*          T     = (float*)(ws + 163840);            // 2097152
    unsigned short* expB  = (unsigned short*)(ws + 2260992);  // 33554432
    unsigned short* expVT = (unsigned short*)(ws + 35815424); // 33554432
    float*          T_part= (float*)(ws + 69369856);          // np*2097152

    int np = 16;
    while (np > 1 && 69369856ull + (size_t)np * 2097152 + 2097152 > ws_size) np >>= 1;

    unsigned short* Gth = (unsigned short*)(ws + 69369856 + (size_t)np * 2097152);
    unsigned short* Gtm = Gth + 128 * 128 * 32;

    hipMemsetAsync(Zcat, 0, 32768, stream);   // Zcat only (T fully written by k2b)

    k0_prep <<<dim3(32),     256, 0, stream>>>(wB, wV, Wh, Wl);
    k1_fused<<<dim3(16, 32), 256, 0, stream>>>(x, Wh, Wl, bB, bV, expB, expVT, Zcat);
    k2_T    <<<dim3(np, 32), 256, 0, stream>>>(x, expB, T_part, np);
    k2b_red <<<dim3(512),    256, 0, stream>>>(T_part, T, np);
    k3b_G   <<<dim3(8, 32),  256, 0, stream>>>(T, wA, bA, Zcat, Gth, Gtm);
    k4_out  <<<dim3(32, 32), 256, 0, stream>>>(expVT, Gth, Gtm, out);
}